// Round 5
// baseline (8305.604 us; speedup 1.0000x reference)
//
#include <hip/hip_runtime.h>

// 2-layer LSTM (B=64, T=2048, H=256), persistent kernel, DUAL-XCD edition.
// R10 = R9 with the prefetch RACE fixed:
//  - R9 prefetched A-fragments with inline-asm global_load into registers
//    consumed on the NEXT loop iteration. The compiler treats asm outputs as
//    synchronously produced, so back-edge phi copies / spills of those
//    registers could be scheduled BEFORE the data returned -> garbage
//    (non-deterministic absmax 468 / 0.60). Fix: ALL device-written-data
//    loads are __hip_atomic_load(RELAXED, AGENT) (= global_load sc0, L1
//    bypass), which the compiler understands and fences correctly.
//  - Stamp now sits directly after the poll, preceded by a free
//    s_waitcnt vmcnt(0) asm (poll already drained all prior VMEM including
//    the h store) -- pins store-before-stamp at compiler + HW level.
// Structure (from R8/R9): two XCD groups x 32 WGs; per group, 2 batch
// subgroups alternate phases (phase p: sub=p&1, t=p>>1 -> L0(t), L1(t-1),
// FC(t-2)); every dependency is 1 phase old at its prefetch point and
// licensed by the end-of-phase poll (all 128 wave-flags >= p).
// Slot-reuse safety: writer at phase q overwrites a slot last read by
// prefetches issued at end of q-3, drained at top of q-2, before those waves
// stamped q-1; writer polls >= q-1 first. Coherence: sc0/atomic loads for
// all device-written lines, plain write-through stores, XCD-local L2 as the
// coherency point (same family as verified R6/R7).

#define NWGX 32     // participant WGs per XCD group
#define SB   16     // batches per subgroup
#define TT   2048
#define HH   256
#define HS   8      // hidden dims per WG (strip)
#define NPH  (2*TT+4)

// workspace layout (dwords)
#define WS_H0    0        // [g2][sub2][par2][strip32][bl16][dim8] bf16 = 16384 dw
#define WS_H1    16384    // same, 16384 dw
#define WS_FLAGS 32768    // 2 groups x 128 wave-flags x 4 dw stride = 1024 dw
#define WS_CNT   33792    // 16 dw
#define WS_NWIN  33808    // 1 dw
#define WS_NZERO 33809    // zeroed [0, WS_NZERO)
#define WS_WIN   33812    // 2 dw -- OUTSIDE zeroed region

typedef float  f32x4  __attribute__((ext_vector_type(4)));
typedef __bf16 bf16x8 __attribute__((ext_vector_type(8)));
typedef unsigned long long u64;
typedef unsigned int u32;

__device__ __forceinline__ float sigf(float x)   { return 1.0f / (1.0f + __expf(-x)); }
__device__ __forceinline__ float tanh_f(float x) { return 2.0f / (1.0f + __expf(-2.0f * x)) - 1.0f; }

__device__ __forceinline__ bf16x8 mk8(u64 lo, u64 hi) {
  union { u64 u[2]; bf16x8 v; } c;
  c.u[0] = lo; c.u[1] = hi;
  return c.v;
}

__device__ __forceinline__ u64 ald(const void* p) {
  return __hip_atomic_load((const u64*)p, __ATOMIC_RELAXED,
                           __HIP_MEMORY_SCOPE_AGENT);
}

template<int N> struct ic { static constexpr int v = N; };

__global__ void init_ws(u32* ws) {
  int i = blockIdx.x * blockDim.x + threadIdx.x;
  for (; i < WS_NZERO; i += gridDim.x * blockDim.x) ws[i] = 0u;
  if (blockIdx.x == 0 && threadIdx.x == 0) {
    ((int*)ws)[WS_WIN] = -1;       // outside the zeroed range: no race
    ((int*)ws)[WS_WIN + 1] = -1;
  }
}

__global__ __launch_bounds__(256, 1) void lstm2_persistent(
    const float* __restrict__ y,
    const float* __restrict__ Wih0, const float* __restrict__ Whh0,
    const float* __restrict__ bih0, const float* __restrict__ bhh0,
    const float* __restrict__ Wih1, const float* __restrict__ Whh1,
    const float* __restrict__ bih1, const float* __restrict__ bhh1,
    const float* __restrict__ Wfc,  const float* __restrict__ bfc,
    float* __restrict__ out,
    u32* __restrict__ ws)
{
  __bf16* h0buf  = (__bf16*)(ws + WS_H0);
  __bf16* h1buf  = (__bf16*)(ws + WS_H1);
  int*    flags  = (int*)(ws + WS_FLAGS);
  int*    cnt    = (int*)(ws + WS_CNT);
  int*    nwin   = (int*)(ws + WS_NWIN);
  int*    winners= (int*)(ws + WS_WIN);

  const int tid = threadIdx.x;

  // ---- dual-XCD election: first 32 registrants on TWO XCDs participate ----
  __shared__ int s_w, s_g;
  if (tid == 0) {
    // HW_REG_XCC_ID = 20, offset 0, size 32 -> imm = 20 | (31<<11)
    int xcc = __builtin_amdgcn_s_getreg(20 | (31 << 11)) & 0xF;
    int r = atomicAdd(&cnt[xcc], 1);               // device-scope, one-time
    if (r == NWGX - 1) {                           // 32nd registrant claims a slot
      int slot = atomicAdd(nwin, 1);
      if (slot < 2)
        __hip_atomic_store(&winners[slot], xcc, __ATOMIC_RELAXED,
                           __HIP_MEMORY_SCOPE_AGENT);
    }
    int gg = -1;
    if (r < NWGX) {
      int w0v, w1v;
      do {
        w0v = __hip_atomic_load(&winners[0], __ATOMIC_RELAXED, __HIP_MEMORY_SCOPE_AGENT);
        w1v = __hip_atomic_load(&winners[1], __ATOMIC_RELAXED, __HIP_MEMORY_SCOPE_AGENT);
      } while (w0v == -1 || w1v == -1);
      if (xcc == w0v) gg = 0; else if (xcc == w1v) gg = 1;
    }
    s_w = r; s_g = gg;
  }
  __syncthreads();
  const int w = s_w, g = s_g;
  if (g < 0 || w >= NWGX) return;   // non-participant exits, frees its CU

  const int wave = tid >> 6;    // 0..3
  const int lane = tid & 63;
  const int ly   = wave >> 1;   // 0: layer0, 1: layer1
  const int nn   = wave & 1;    // dim-half (dims nn*4 .. nn*4+3 of this WG's 8)
  const int ml   = lane & 15;   // MFMA: A row (batch) / B col (local gate row)
  const int kq   = lane >> 4;   // MFMA k-quad
  const int bt   = lane >> 2;   // epilogue batch-in-sub (0..15)
  const int dloc = lane & 3;    // epilogue dim within half

  __shared__ float tile[4][16][20];   // per-wave gate transpose tile (private)

  // ---- recurrent weights -> VGPR B-fragments ----
  // local gate row r=ml within this wave's tile: gate = ml&3, dim = nn*4+(ml>>2)
  bf16x8 wA[16];   // L0 waves use [0..7] (K=256); L1 waves use [0..15] (K=512)
  {
    const int rglob = (ml & 3) * 256 + w * HS + nn * 4 + (ml >> 2);
    if (ly == 0) {
      #pragma unroll
      for (int s = 0; s < 8; s++) {
        const float* src = Whh0 + rglob * HH + s * 32 + kq * 8;
        bf16x8 f;
        #pragma unroll
        for (int j = 0; j < 8; j++) f[j] = (__bf16)src[j];
        wA[s] = f;
      }
    } else {
      #pragma unroll
      for (int s = 0; s < 16; s++) {
        const int k = s * 32 + kq * 8;
        const float* src = (k < 256) ? (Wih1 + rglob * HH + k)
                                     : (Whh1 + rglob * HH + (k - 256));
        bf16x8 f;
        #pragma unroll
        for (int j = 0; j < 8; j++) f[j] = (__bf16)src[j];
        wA[s] = f;
      }
    }
  }

  // ---- per-thread epilogue constants in registers ----
  float bc[4];        // per-gate bias (bih+bhh)
  float wx[4][4];     // L0 only: Wih0 rows
  {
    const int dgl = w * HS + nn * 4 + dloc;
    #pragma unroll
    for (int q = 0; q < 4; q++) {
      const int rg = q * 256 + dgl;
      if (ly == 0) {
        bc[q] = bih0[rg] + bhh0[rg];
        #pragma unroll
        for (int j = 0; j < 4; j++) wx[q][j] = Wih0[rg * 4 + j];
      } else {
        bc[q] = bih1[rg] + bhh1[rg];
      }
    }
  }

  // ---- FC constants (wave 0 handles one (batch, class) task per phase) ----
  float wfc[4] = {0.f, 0.f, 0.f, 0.f};
  float bfcv = 0.f;
  const int fcb = w & 15;     // batch-in-sub
  const int fcc = w >> 4;     // class
  if (wave == 0) {
    #pragma unroll
    for (int j = 0; j < 4; j++) wfc[j] = Wfc[fcc * HH + lane * 4 + j];
    bfcv = bfc[fcc];
  }

  // lane-constant address pieces (bf16-element offsets within a slot)
  const int aLane  = (kq * SB + ml) * HS;                       // + s*512
  const int pubOff = (w * SB + bt) * HS + nn * 4 + dloc;
  const int fcOff  = ((lane >> 1) * SB + fcb) * HS + (lane & 1) * 4;

  float cs0 = 0.f, cs1 = 0.f;   // c-state per subgroup (meaning depends on ly)
  float xw0[4] = {-100.f, -100.f, -100.f, -100.f};
  float xw1[4] = {-100.f, -100.f, -100.f, -100.f};
  u64 a0u[16], a1u[16];         // prefetched A-fragments (compiler-tracked)
  union { u64 u; __bf16 h[4]; } fcd; fcd.u = 0ull;

  // ---- prologue: prefetch phase 0 inputs (zero-initialized buffers) ----
  {
    const int pr0 = 1, pr1 = 0;   // (0-1)&1, 0&1
    const __bf16* a0b = h0buf + ((g * 2 + 0) * 2 + pr0) * 4096 + aLane;
    #pragma unroll
    for (int s = 0; s < 8; s++) {
      a0u[2 * s]     = ald(a0b + s * 512);
      a0u[2 * s + 1] = ald(a0b + s * 512 + 4);
    }
    if (ly == 1) {
      const __bf16* a1b = h1buf + ((g * 2 + 0) * 2 + pr1) * 4096 + aLane;
      #pragma unroll
      for (int s = 0; s < 8; s++) {
        a1u[2 * s]     = ald(a1b + s * 512);
        a1u[2 * s + 1] = ald(a1b + s * 512 + 4);
      }
    }
    if (wave == 0)
      fcd.u = ald(h1buf + ((g * 2 + 0) * 2 + 0) * 4096 + fcOff);
  }

  auto body = [&](int p, auto subc) {
    constexpr int SUB = decltype(subc)::v;
    const int t = p >> 1;
    float& cst = (SUB == 0) ? cs0 : cs1;
    float (&xw)[4] = (SUB == 0) ? xw0 : xw1;

    const bool doL0w = (ly == 0) && (t < TT);
    const bool doL1w = (ly == 1) && (t >= 1 && t <= TT);
    const bool doFCw = (wave == 0) && (t >= 2 && t <= TT + 1);

    float yv = -100.0f;
    if (ly == 0 && t < TT) yv = y[(g * 32 + SUB * 16 + bt) * TT + t];

    f32x4 acc  = {0.f, 0.f, 0.f, 0.f};
    f32x4 accB = {0.f, 0.f, 0.f, 0.f};
    if (doL0w) {
      #pragma unroll
      for (int s = 0; s < 8; s++)
        acc = __builtin_amdgcn_mfma_f32_16x16x32_bf16(
            mk8(a0u[2 * s], a0u[2 * s + 1]), wA[s], acc, 0, 0, 0);
    }
    if (doL1w) {
      #pragma unroll
      for (int s = 0; s < 8; s++)
        acc  = __builtin_amdgcn_mfma_f32_16x16x32_bf16(
            mk8(a0u[2 * s], a0u[2 * s + 1]), wA[s],     acc,  0, 0, 0);
      #pragma unroll
      for (int s = 0; s < 8; s++)
        accB = __builtin_amdgcn_mfma_f32_16x16x32_bf16(
            mk8(a1u[2 * s], a1u[2 * s + 1]), wA[s + 8], accB, 0, 0, 0);
    }

    // per-wave gate transpose through private LDS tile (no cross-wave sync)
    if (doL0w || doL1w) {
      f32x4 sum = acc + accB;
      *(f32x4*)&tile[wave][ml][kq * 4] = sum;
    }
    asm volatile("s_waitcnt lgkmcnt(0)" ::: "memory");

    if (doL0w) {
      xw[0] = xw[1]; xw[1] = xw[2]; xw[2] = xw[3]; xw[3] = yv;
      float gv[4];
      #pragma unroll
      for (int q = 0; q < 4; q++)
        gv[q] = tile[wave][dloc * 4 + q][bt] + bc[q]
              + wx[q][0] * xw[0] + wx[q][1] * xw[1]
              + wx[q][2] * xw[2] + wx[q][3] * xw[3];
      const float cn = sigf(gv[1]) * cst + sigf(gv[0]) * tanh_f(gv[2]);
      cst = cn;
      const float hn = sigf(gv[3]) * tanh_f(cn);
      h0buf[((g * 2 + SUB) * 2 + (t & 1)) * 4096 + pubOff] = (__bf16)hn;
    }
    if (doL1w) {
      float gv[4];
      #pragma unroll
      for (int q = 0; q < 4; q++)
        gv[q] = tile[wave][dloc * 4 + q][bt] + bc[q];
      const float cn = sigf(gv[1]) * cst + sigf(gv[0]) * tanh_f(gv[2]);
      cst = cn;
      const float hn = sigf(gv[3]) * tanh_f(cn);
      h1buf[((g * 2 + SUB) * 2 + ((t - 1) & 1)) * 4096 + pubOff] = (__bf16)hn;
    }

    // FC for timestep t-2 (data prefetched last phase)
    if (doFCw) {
      float s = 0.f;
      #pragma unroll
      for (int j = 0; j < 4; j++) s += (float)fcd.h[j] * wfc[j];
      #pragma unroll
      for (int off = 32; off > 0; off >>= 1) s += __shfl_down(s, off, 64);
      if (lane == 0)
        out[(g * 32 + SUB * 16 + fcb) * (TT * 2) + (t - 2) * 2 + fcc] = s + bfcv;
    }

    // ---- poll enabling phase p+1: all 128 group wave-flags >= p ----
    {
      int* f0 = &flags[(g * 128 + lane) * 4];
      int* f1 = &flags[(g * 128 + 64 + lane) * 4];
      int a, b;
      do {
        a = __hip_atomic_load(f0, __ATOMIC_RELAXED, __HIP_MEMORY_SCOPE_AGENT);
        b = __hip_atomic_load(f1, __ATOMIC_RELAXED, __HIP_MEMORY_SCOPE_AGENT);
      } while (!__all((a < b ? a : b) >= p));
    }

    // poll's waits already drained all prior VMEM (incl. the h store);
    // this asm is free and PINS the h store before the stamp (compiler+HW).
    asm volatile("s_waitcnt vmcnt(0)" ::: "memory");
    if (lane == 0)
      __hip_atomic_store(&flags[(g * 128 + w * 4 + wave) * 4], p + 1,
                         __ATOMIC_RELAXED, __HIP_MEMORY_SCOPE_WORKGROUP);

    // ---- prefetch phase p+1 inputs (licensed by the poll above) ----
    {
      const int tn  = (p + 1) >> 1;
      constexpr int SUBN = SUB ^ 1;
      const int pr0 = (tn - 1) & 1;
      const int pr1 = tn & 1;
      const __bf16* a0b = h0buf + ((g * 2 + SUBN) * 2 + pr0) * 4096 + aLane;
      #pragma unroll
      for (int s = 0; s < 8; s++) {
        a0u[2 * s]     = ald(a0b + s * 512);
        a0u[2 * s + 1] = ald(a0b + s * 512 + 4);
      }
      if (ly == 1) {
        const __bf16* a1b = h1buf + ((g * 2 + SUBN) * 2 + pr1) * 4096 + aLane;
        #pragma unroll
        for (int s = 0; s < 8; s++) {
          a1u[2 * s]     = ald(a1b + s * 512);
          a1u[2 * s + 1] = ald(a1b + s * 512 + 4);
        }
      }
      if (wave == 0)
        fcd.u = ald(h1buf + ((g * 2 + SUBN) * 2 + (tn & 1)) * 4096 + fcOff);
    }
  };

  for (int ph = 0; ph < NPH; ph += 2) {
    body(ph,     ic<0>{});
    body(ph + 1, ic<1>{});
  }
}

extern "C" void kernel_launch(void* const* d_in, const int* in_sizes, int n_in,
                              void* d_out, int out_size, void* d_ws, size_t ws_size,
                              hipStream_t stream) {
  u32* ws = (u32*)d_ws;
  init_ws<<<dim3(64), dim3(256), 0, stream>>>(ws);
  lstm2_persistent<<<dim3(768), dim3(256), 0, stream>>>(
      (const float*)d_in[0],  (const float*)d_in[1], (const float*)d_in[2],
      (const float*)d_in[3],  (const float*)d_in[4], (const float*)d_in[5],
      (const float*)d_in[6],  (const float*)d_in[7], (const float*)d_in[8],
      (const float*)d_in[9],  (const float*)d_in[10],
      (float*)d_out, ws);
}